// Round 3
// baseline (119.944 us; speedup 1.0000x reference)
//
#include <hip/hip_runtime.h>

// Depthwise causal 1D conv, B=4, C=4096, L=4096, K=4, PAD=3.
// y[b,c,t] = sum_{k=0..3} w[c,k] * x[b,c,t-3+k] + bias[c], t in [0, 4099)
// x index outside [0,4096) -> 0.
// kernel layout (K,1,C): kern[k*C + c].  out: (B, C, 4099) flat.
//
// Alignment trick: 4099 % 4 == 3, so output flat index (r*4099 + t) is
// 16B-aligned iff t ≡ r (mod 4). Per row: s = r&3 lead scalars,
// 512 aligned 8-output pairs, (3-s) tail scalars.
// R3: removed nontemporal store hint — nt bypassed L2 write-combining and
// inflated WRITE_SIZE 268.6 -> 293.6 MB (partial 64B lines to HBM).

#define CONV_L 4096
#define CONV_C 4096
#define CONV_OUTL 4099

typedef float f4 __attribute__((ext_vector_type(4)));

__device__ __forceinline__ float xget(const float* __restrict__ xr, int i) {
    return (i >= 0 && i < CONV_L) ? xr[i] : 0.0f;
}

__device__ __forceinline__ f4 mkf4(float a, float b, float c, float d) {
    f4 v; v.x = a; v.y = b; v.z = c; v.w = d; return v;
}

__global__ __launch_bounds__(256) void conv1d_dw_kernel(
    const float* __restrict__ x,
    const float* __restrict__ kern,
    const float* __restrict__ bias,
    float* __restrict__ out)
{
    const int row = blockIdx.x;            // row = b*C + c
    const int c   = row & (CONV_C - 1);
    const int s   = row & 3;               // alignment phase of this output row

    const float w0 = kern[c];
    const float w1 = kern[CONV_C + c];
    const float w2 = kern[2 * CONV_C + c];
    const float w3 = kern[3 * CONV_C + c];
    const float bv = bias[c];

    const float* __restrict__ xr = x + (size_t)row * CONV_L;
    float* __restrict__ yr       = out + (size_t)row * CONV_OUTL;

    // Lead scalars t in [0,s) and tail scalars t in [s+4096, 4099):
    // combined, threads 0..2 each do at most one: t = tid < s ? tid : 4096+tid.
    if (threadIdx.x < 3) {
        const int t = (threadIdx.x < (unsigned)s) ? (int)threadIdx.x
                                                  : (int)(4096 + threadIdx.x);
        if (t < CONV_OUTL) {
            float y = bv;
            y = fmaf(w0, xget(xr, t - 3), y);
            y = fmaf(w1, xget(xr, t - 2), y);
            y = fmaf(w2, xget(xr, t - 1), y);
            y = fmaf(w3, xget(xr, t    ), y);
            yr[t] = y;
        }
    }

    // Main body: 512 pairs of aligned float4 stores; pair p covers
    // t in [s+8p, s+8p+8). Each thread does p = tid and p = tid+256.
#pragma unroll
    for (int it = 0; it < 2; ++it) {
        const int p  = (int)threadIdx.x + it * 256;
        const int t0 = s + (p << 3);

        f4 a, b, cc;
        b = *(const f4*)(xr + t0);                 // x[t0..t0+3], always in range
        if (p == 0) {                              // x[s-4..s-1], needs zero pad
            a = mkf4(xget(xr, s - 4), xget(xr, s - 3),
                     xget(xr, s - 2), xget(xr, s - 1));
        } else {
            a = *(const f4*)(xr + t0 - 4);         // dword-aligned dwordx4: OK
        }
        if (p == 511 && s != 0) {                  // x[t0+4..t0+7] crosses 4096
            cc = mkf4(xget(xr, t0 + 4), xget(xr, t0 + 5),
                      xget(xr, t0 + 6), xget(xr, t0 + 7));
        } else {
            cc = *(const f4*)(xr + t0 + 4);
        }

        f4 y0, y1;
        y0.x = fmaf(w0, a.y,  fmaf(w1, a.z,  fmaf(w2, a.w,  fmaf(w3, b.x,  bv))));
        y0.y = fmaf(w0, a.z,  fmaf(w1, a.w,  fmaf(w2, b.x,  fmaf(w3, b.y,  bv))));
        y0.z = fmaf(w0, a.w,  fmaf(w1, b.x,  fmaf(w2, b.y,  fmaf(w3, b.z,  bv))));
        y0.w = fmaf(w0, b.x,  fmaf(w1, b.y,  fmaf(w2, b.z,  fmaf(w3, b.w,  bv))));
        y1.x = fmaf(w0, b.y,  fmaf(w1, b.z,  fmaf(w2, b.w,  fmaf(w3, cc.x, bv))));
        y1.y = fmaf(w0, b.z,  fmaf(w1, b.w,  fmaf(w2, cc.x, fmaf(w3, cc.y, bv))));
        y1.z = fmaf(w0, b.w,  fmaf(w1, cc.x, fmaf(w2, cc.y, fmaf(w3, cc.z, bv))));
        y1.w = fmaf(w0, cc.x, fmaf(w1, cc.y, fmaf(w2, cc.z, fmaf(w3, cc.w, bv))));

        // 16B-aligned stores through L2 (write-combining into full lines).
        *(f4*)(yr + t0)     = y0;
        *(f4*)(yr + t0 + 4) = y1;
    }
}

extern "C" void kernel_launch(void* const* d_in, const int* in_sizes, int n_in,
                              void* d_out, int out_size, void* d_ws, size_t ws_size,
                              hipStream_t stream)
{
    const float* x    = (const float*)d_in[0];   // (B, C, L)
    const float* kern = (const float*)d_in[1];   // (K, 1, C)
    const float* bias = (const float*)d_in[2];   // (C,)
    float* out        = (float*)d_out;           // (B, C, 4099)

    const int rows = 4 * CONV_C;                 // B * C = 16384
    conv1d_dw_kernel<<<rows, 256, 0, stream>>>(x, kern, bias, out);
}

// Round 4
// 92.769 us; speedup vs baseline: 1.2929x; 1.2929x over previous
//
#include <hip/hip_runtime.h>

// Depthwise causal 1D conv, B=4, C=4096, L=4096, K=4, PAD=3.
// y[b,c,t] = sum_{k=0..3} w[c,k] * x[b,c,t-3+k] + bias[c], t in [0, 4099)
// x index outside [0,4096) -> 0.
// kernel layout (K,1,C): kern[k*C + c].  out: (B, C, 4099) flat.
//
// Alignment trick: 4099 % 4 == 3, so output flat index (r*4099 + t) is
// 16B-aligned iff t ≡ r (mod 4). Per row: s = r&3 lead scalars,
// 1024 aligned float4 groups, (3-s) tail scalars.
//
// R4 lessons baked in:
//  - nt stores are REQUIRED: they keep the 268MB output stream out of L3,
//    which lets L3 retain ~half of x (FETCH 268->134MB). R3 (no nt) = 120us.
//  - each store INSTRUCTION must be wave-contiguous for nt write-combining:
//    one f4 per thread per iteration (64 lanes x 16B = 1KB solid), not two
//    strided f4s per thread (R2: +9% WRITE_SIZE from partial 64B lines).

#define CONV_L 4096
#define CONV_C 4096
#define CONV_OUTL 4099

typedef float f4 __attribute__((ext_vector_type(4)));

__device__ __forceinline__ float xget(const float* __restrict__ xr, int i) {
    return (i >= 0 && i < CONV_L) ? xr[i] : 0.0f;
}

__device__ __forceinline__ f4 mkf4(float a, float b, float c, float d) {
    f4 v; v.x = a; v.y = b; v.z = c; v.w = d; return v;
}

__global__ __launch_bounds__(256) void conv1d_dw_kernel(
    const float* __restrict__ x,
    const float* __restrict__ kern,
    const float* __restrict__ bias,
    float* __restrict__ out)
{
    const int row = blockIdx.x;            // row = b*C + c
    const int c   = row & (CONV_C - 1);
    const int s   = row & 3;               // alignment phase of this output row

    const float w0 = kern[c];
    const float w1 = kern[CONV_C + c];
    const float w2 = kern[2 * CONV_C + c];
    const float w3 = kern[3 * CONV_C + c];
    const float bv = bias[c];

    const float* __restrict__ xr = x + (size_t)row * CONV_L;
    float* __restrict__ yr       = out + (size_t)row * CONV_OUTL;

    // Lead scalars t in [0,s) and tail scalars t in [s+4096, 4099):
    // combined, threads 0..2 each do at most one: t = tid < s ? tid : 4096+tid.
    if (threadIdx.x < 3) {
        const int t = (threadIdx.x < (unsigned)s) ? (int)threadIdx.x
                                                  : (int)(4096 + threadIdx.x);
        if (t < CONV_OUTL) {
            float y = bv;
            y = fmaf(w0, xget(xr, t - 3), y);
            y = fmaf(w1, xget(xr, t - 2), y);
            y = fmaf(w2, xget(xr, t - 1), y);
            y = fmaf(w3, xget(xr, t    ), y);
            yr[t] = y;
        }
    }

    // Main body: 1024 aligned f4 groups; group g covers t in [s+4g, s+4g+4).
    // Thread tid handles g = tid + 256*it, it = 0..3 -> every store
    // instruction is wave-contiguous (1KB per wave).
#pragma unroll
    for (int it = 0; it < 4; ++it) {
        const int g  = (int)threadIdx.x + it * 256;
        const int t0 = s + (g << 2);

        f4 a, b;
        if (g == 0) {                               // x[s-4..s-1]: zero pad
            a = mkf4(xget(xr, s - 4), xget(xr, s - 3),
                     xget(xr, s - 2), xget(xr, s - 1));
        } else {
            a = *(const f4*)(xr + t0 - 4);          // dword-aligned dwordx4
        }
        if (g == 1023 && s != 0) {                  // x[t0..t0+3] crosses 4096
            b = mkf4(xget(xr, t0), xget(xr, t0 + 1),
                     xget(xr, t0 + 2), xget(xr, t0 + 3));
        } else {
            b = *(const f4*)(xr + t0);
        }

        f4 y0;
        y0.x = fmaf(w0, a.y, fmaf(w1, a.z, fmaf(w2, a.w, fmaf(w3, b.x, bv))));
        y0.y = fmaf(w0, a.z, fmaf(w1, a.w, fmaf(w2, b.x, fmaf(w3, b.y, bv))));
        y0.z = fmaf(w0, a.w, fmaf(w1, b.x, fmaf(w2, b.y, fmaf(w3, b.z, bv))));
        y0.w = fmaf(w0, b.x, fmaf(w1, b.y, fmaf(w2, b.z, fmaf(w3, b.w, bv))));

        // 16B-aligned, wave-contiguous, L3-bypassing store.
        __builtin_nontemporal_store(y0, (f4*)(yr + t0));
    }
}

extern "C" void kernel_launch(void* const* d_in, const int* in_sizes, int n_in,
                              void* d_out, int out_size, void* d_ws, size_t ws_size,
                              hipStream_t stream)
{
    const float* x    = (const float*)d_in[0];   // (B, C, L)
    const float* kern = (const float*)d_in[1];   // (K, 1, C)
    const float* bias = (const float*)d_in[2];   // (C,)
    float* out        = (float*)d_out;           // (B, C, 4099)

    const int rows = 4 * CONV_C;                 // B * C = 16384
    conv1d_dw_kernel<<<rows, 256, 0, stream>>>(x, kern, bias, out);
}

// Round 5
// 83.928 us; speedup vs baseline: 1.4291x; 1.1053x over previous
//
#include <hip/hip_runtime.h>

// Depthwise causal 1D conv, B=4, C=4096, L=4096, K=4, PAD=3.
// y[b,c,t] = sum_{k=0..3} w[c,k] * x[b,c,t-3+k] + bias[c], t in [0, 4099)
// x index outside [0,4096) -> 0.
// kernel layout (K,1,C): kern[k*C + c].  out: (B, C, 4099) flat.
//
// Alignment trick: 4099 % 4 == 3, so output flat index (r*4099 + t) is
// 16B-aligned iff t ≡ r (mod 4). Per row: s = r&3 lead scalars,
// 1024 aligned float4 groups, (3-s) tail scalars.
//
// Lessons baked in:
//  - nt stores REQUIRED (keep 268MB output out of L3 so L3 retains x;
//    R3 without nt = 120us vs 92.8us).
//  - every store instruction wave-contiguous (64x16B solid) for nt
//    write-combining (R2: strided pairs -> +9% WRITE_SIZE).
//  - R5: batch ALL 8 loads before compute. R4's VGPR_Count=16 proved the
//    compiler serialized iterations (MLP=2 loads/wave); issue-all-then-
//    compute forces 8 loads in flight per wave.

#define CONV_L 4096
#define CONV_C 4096
#define CONV_OUTL 4099

typedef float f4 __attribute__((ext_vector_type(4)));

__device__ __forceinline__ float xget(const float* __restrict__ xr, int i) {
    return (i >= 0 && i < CONV_L) ? xr[i] : 0.0f;
}

__device__ __forceinline__ f4 mkf4(float a, float b, float c, float d) {
    f4 v; v.x = a; v.y = b; v.z = c; v.w = d; return v;
}

__global__ __launch_bounds__(256) void conv1d_dw_kernel(
    const float* __restrict__ x,
    const float* __restrict__ kern,
    const float* __restrict__ bias,
    float* __restrict__ out)
{
    const int row = blockIdx.x;            // row = b*C + c
    const int c   = row & (CONV_C - 1);
    const int s   = row & 3;               // alignment phase of this output row

    const float w0 = kern[c];
    const float w1 = kern[CONV_C + c];
    const float w2 = kern[2 * CONV_C + c];
    const float w3 = kern[3 * CONV_C + c];
    const float bv = bias[c];

    const float* __restrict__ xr = x + (size_t)row * CONV_L;
    float* __restrict__ yr       = out + (size_t)row * CONV_OUTL;

    // ---- Phase 1: issue ALL loads (8 dwordx4 in flight per thread) ----
    f4 a[4], b[4];
#pragma unroll
    for (int it = 0; it < 4; ++it) {
        const int g  = (int)threadIdx.x + it * 256;
        const int t0 = s + (g << 2);
        if (it == 3 && g == 1023 && s != 0) {       // x[t0..t0+3] crosses 4096
            b[it] = mkf4(xget(xr, t0), xget(xr, t0 + 1),
                         xget(xr, t0 + 2), xget(xr, t0 + 3));
        } else {
            b[it] = *(const f4*)(xr + t0);
        }
        if (it == 0 && g == 0) {                    // x[s-4..s-1]: zero pad
            a[it] = mkf4(xget(xr, s - 4), xget(xr, s - 3),
                         xget(xr, s - 2), xget(xr, s - 1));
        } else {
            a[it] = *(const f4*)(xr + t0 - 4);      // dword-aligned dwordx4
        }
    }

    // ---- Phase 2: compute + wave-contiguous nt stores ----
#pragma unroll
    for (int it = 0; it < 4; ++it) {
        const int g  = (int)threadIdx.x + it * 256;
        const int t0 = s + (g << 2);

        f4 y0;
        y0.x = fmaf(w0, a[it].y, fmaf(w1, a[it].z, fmaf(w2, a[it].w, fmaf(w3, b[it].x, bv))));
        y0.y = fmaf(w0, a[it].z, fmaf(w1, a[it].w, fmaf(w2, b[it].x, fmaf(w3, b[it].y, bv))));
        y0.z = fmaf(w0, a[it].w, fmaf(w1, b[it].x, fmaf(w2, b[it].y, fmaf(w3, b[it].z, bv))));
        y0.w = fmaf(w0, b[it].x, fmaf(w1, b[it].y, fmaf(w2, b[it].z, fmaf(w3, b[it].w, bv))));

        __builtin_nontemporal_store(y0, (f4*)(yr + t0));
    }

    // ---- Lead/tail scalars last (divergent; don't stall the main loads) ----
    // t in [0,s) and [s+4096, 4099): threads 0..2 each do at most one.
    if (threadIdx.x < 3) {
        const int t = (threadIdx.x < (unsigned)s) ? (int)threadIdx.x
                                                  : (int)(4096 + threadIdx.x);
        if (t < CONV_OUTL) {
            float y = bv;
            y = fmaf(w0, xget(xr, t - 3), y);
            y = fmaf(w1, xget(xr, t - 2), y);
            y = fmaf(w2, xget(xr, t - 1), y);
            y = fmaf(w3, xget(xr, t    ), y);
            yr[t] = y;
        }
    }
}

extern "C" void kernel_launch(void* const* d_in, const int* in_sizes, int n_in,
                              void* d_out, int out_size, void* d_ws, size_t ws_size,
                              hipStream_t stream)
{
    const float* x    = (const float*)d_in[0];   // (B, C, L)
    const float* kern = (const float*)d_in[1];   // (K, 1, C)
    const float* bias = (const float*)d_in[2];   // (C,)
    float* out        = (float*)d_out;           // (B, C, 4099)

    const int rows = 4 * CONV_C;                 // B * C = 16384
    conv1d_dw_kernel<<<rows, 256, 0, stream>>>(x, kern, bias, out);
}